// Round 4
// baseline (992.320 us; speedup 1.0000x reference)
//
#include <hip/hip_runtime.h>
#include <hip/hip_bf16.h>
#include <stdint.h>

typedef __attribute__((ext_vector_type(8))) short short8;
typedef __attribute__((ext_vector_type(8))) unsigned short ushort8;
typedef __attribute__((ext_vector_type(4))) float f32x4;

#define K_DIM 4096
#define N_DIM 11008
#define M_DIM 8192
#define BM 256
#define BN 256
#define BK 64
#define TILES (K_DIM / BK)   // 64

__constant__ float c_nf4[16] = {
    -1.0f, -0.6961928009986877f, -0.5250730514526367f, -0.39491748809814453f,
    -0.28444138169288635f, -0.18477343022823334f, -0.09105003625154495f, 0.0f,
    0.07958029955625534f, 0.16093020141124725f, 0.24611230194568634f,
    0.33791524171829224f, 0.44070982933044434f, 0.5626170039176941f,
    0.7229568362236023f, 1.0f};

__device__ __forceinline__ unsigned short f2bf(float f) {
    uint32_t u = __float_as_uint(f);
    u += 0x7fffu + ((u >> 16) & 1u);   // round-to-nearest-even (finite inputs)
    return (unsigned short)(u >> 16);
}

__global__ __launch_bounds__(256) void nf4_dequant_w(const int* __restrict__ q,
                                                     const float* __restrict__ absmax,
                                                     unsigned short* __restrict__ w) {
    __shared__ float lut[16];
    if (threadIdx.x < 16) lut[threadIdx.x] = c_nf4[threadIdx.x];
    __syncthreads();
    size_t t = (size_t)blockIdx.x * 256 + threadIdx.x;
    const int4* q4 = (const int4*)q;
    int4 qa = q4[2 * t];
    int4 qb = q4[2 * t + 1];
    float s = absmax[t >> 3];
    ushort8 o;
    o[0] = f2bf(lut[qa.x & 15] * s);
    o[1] = f2bf(lut[qa.y & 15] * s);
    o[2] = f2bf(lut[qa.z & 15] * s);
    o[3] = f2bf(lut[qa.w & 15] * s);
    o[4] = f2bf(lut[qb.x & 15] * s);
    o[5] = f2bf(lut[qb.y & 15] * s);
    o[6] = f2bf(lut[qb.z & 15] * s);
    o[7] = f2bf(lut[qb.w & 15] * s);
    ((ushort8*)w)[t] = o;
}

__global__ __launch_bounds__(256) void x_to_bf16(const float* __restrict__ x,
                                                 unsigned short* __restrict__ xb) {
    size_t t = (size_t)blockIdx.x * 256 + threadIdx.x;
    const float4* x4 = (const float4*)x;
    float4 a = x4[2 * t];
    float4 b = x4[2 * t + 1];
    ushort8 o;
    o[0] = f2bf(a.x); o[1] = f2bf(a.y); o[2] = f2bf(a.z); o[3] = f2bf(a.w);
    o[4] = f2bf(b.x); o[5] = f2bf(b.y); o[6] = f2bf(b.z); o[7] = f2bf(b.w);
    ((ushort8*)xb)[t] = o;
}

// Stage one 128-row half (16 KB) of a [256][64] bf16 tile: 2 gloads/thread.
// LDS dest linear (HW rule); GLOBAL source chunk pre-swizzled (rule 21):
// LDS slot (row r, s) holds global chunk c = s ^ (r&7)  [G4 swizzle, 128B rows].
#define STAGE_HALF(gbase, region, j, k0)                                    \
  do {                                                                      \
    _Pragma("unroll")                                                       \
    for (int _g = 0; _g < 2; ++_g) {                                        \
      const int _D = _g * 512 + tid;       /* slot index 0..1023 */         \
      const int _r = (j) * 128 + (_D >> 3);                                 \
      const int _c = (_D & 7) ^ (_r & 7);  /* source chunk */               \
      __builtin_amdgcn_global_load_lds(                                     \
          (const __attribute__((address_space(1))) void*)((gbase) +         \
              (size_t)_r * K_DIM + (k0) + _c * 8),                          \
          (__attribute__((address_space(3))) void*)((region) +              \
              ((j) * 1024 + _g * 512 + wave * 64) * 8),                     \
          16, 0, 0);                                                        \
    }                                                                       \
  } while (0)

#define READS(kksel)                                                        \
  do {                                                                      \
    _Pragma("unroll")                                                       \
    for (int mi = 0; mi < 8; ++mi)                                          \
      af[mi] = *(const short8*)(Ar + wm * 8192 + mi * 1024 + (roff ^ (kksel))); \
    _Pragma("unroll")                                                       \
    for (int ni = 0; ni < 4; ++ni)                                          \
      bf[ni] = *(const short8*)(Br + wn * 4096 + ni * 1024 + (roff ^ (kksel))); \
  } while (0)

#define MFMA32                                                              \
  do {                                                                      \
    _Pragma("unroll")                                                       \
    for (int mi = 0; mi < 8; ++mi) {                                        \
      _Pragma("unroll")                                                     \
      for (int ni = 0; ni < 4; ++ni)                                        \
        acc[mi][ni] = __builtin_amdgcn_mfma_f32_16x16x32_bf16(              \
            af[mi], bf[ni], acc[mi][ni], 0, 0, 0);                          \
    }                                                                       \
  } while (0)

// 256x256 tile, BK=64, 8 waves (2M x 4N), dbuf-2 with half-tile staging,
// counted vmcnt(4) twice per tile, G4 LDS swizzle, 2 barriers per tile.
__global__ __launch_bounds__(512, 2) void gemm256(const unsigned short* __restrict__ A,
                                                  const unsigned short* __restrict__ B,
                                                  const float* __restrict__ bias,
                                                  float* __restrict__ C) {
    __shared__ unsigned short As[2][BM * BK];   // 2 x 32 KB
    __shared__ unsigned short Bs[2][BN * BK];   // 2 x 32 KB -> 128 KB total

    const int tid  = threadIdx.x;
    const int wave = tid >> 6;
    const int lane = tid & 63;
    const int wm = wave >> 2;               // 0..1 -> 128-row slab of A
    const int wn = wave & 3;                // 0..3 -> 64-row slab of B
    const int lr = lane & 15;
    const int q  = lane >> 4;               // 0..3 (k-quarter)
    // Swizzled per-lane read offset (elements), kk=0; kk=32 is roff ^ 32.
    const int roff = lr * 64 + ((q ^ (lr & 7)) << 3);
    const int early = (wave < 2);           // wm==0 && wn<2: halves in batch1

    // XCD-aware bijective swizzle: grid = 1376, 1376 % 8 == 0.
    const int nbn = N_DIM / BN;             // 43
    const int cpx = (int)gridDim.x >> 3;    // 172
    const int bid = (int)blockIdx.x;
    const int swz = (bid & 7) * cpx + (bid >> 3);
    const int bm = swz / nbn;
    const int bn = swz % nbn;

    const unsigned short* Ab = A + (size_t)bm * BM * K_DIM;
    const unsigned short* Bb = B + (size_t)bn * BN * K_DIM;

    f32x4 acc[8][4];
#pragma unroll
    for (int i = 0; i < 8; ++i)
#pragma unroll
        for (int j = 0; j < 4; ++j)
#pragma unroll
            for (int v = 0; v < 4; ++v) acc[i][j][v] = 0.0f;

    // Prologue: batch1(0) then batch2(0); wait batch1 landed.
    STAGE_HALF(Ab, &As[0][0], 0, 0); STAGE_HALF(Bb, &Bs[0][0], 0, 0);
    STAGE_HALF(Ab, &As[0][0], 1, 0); STAGE_HALF(Bb, &Bs[0][0], 1, 0);
    asm volatile("s_waitcnt vmcnt(4)" ::: "memory");
    asm volatile("s_barrier" ::: "memory");
    // Steady-state entry invariant: batch1(t) landed, batch2(t) in flight (4).

#pragma unroll 1
    for (int t = 0; t < TILES; ++t) {
        const int p = t & 1;
        const unsigned short* Ar = &As[p][0];
        const unsigned short* Br = &Bs[p][0];
        unsigned short* Aw = &As[p ^ 1][0];
        unsigned short* Bw = &Bs[p ^ 1][0];
        int ts = t + 1; if (ts >= TILES) ts = 0;   // tail wrap: harmless in-bounds stage
        const int k0s = ts * BK;

        short8 af[8], bf[4];

        // batch1(t+1): A-half0 + B-half0 into the write buffer.
        STAGE_HALF(Ab, Aw, 0, k0s);
        STAGE_HALF(Bb, Bw, 0, k0s);
        // Early waves' operand halves (Ah0, Bh0) landed at entry: read now.
        if (early) READS(0);
        // Retire batch2(t): outstanding = b2(t)[4] + b1(t+1)[4] = 8 -> wait to 4.
        asm volatile("s_waitcnt vmcnt(4)" ::: "memory");
        asm volatile("s_barrier" ::: "memory");
        // All four halves of tile t now landed for every wave.
        if (!early) READS(0);
        // batch2(t+1): A-half1 + B-half1.
        STAGE_HALF(Ab, Aw, 1, k0s);
        STAGE_HALF(Bb, Bw, 1, k0s);

        __builtin_amdgcn_s_setprio(1);
        MFMA32;          // kk = 0
        READS(32);       // kk = 32 reads interleave into MFMA shadow
        MFMA32;          // kk = 32
        __builtin_amdgcn_s_setprio(0);

        // Retire batch1(t+1): outstanding = b1(t+1)[4] + b2(t+1)[4] = 8 -> 4.
        asm volatile("s_waitcnt vmcnt(4)" ::: "memory");
        asm volatile("s_barrier" ::: "memory");
    }
    // Drain remaining DMA before block retire (LDS dealloc safety).
    asm volatile("s_waitcnt vmcnt(0)" ::: "memory");

    // Epilogue: C/D layout col = lane&15, row = (lane>>4)*4 + v (m89/m91).
    const int row0 = bm * BM + wm * 128 + (q << 2);
    const int col0 = bn * BN + wn * 64 + lr;
#pragma unroll
    for (int ni = 0; ni < 4; ++ni) {
        const int col = col0 + ni * 16;
        const float bv = bias[col];
#pragma unroll
        for (int mi = 0; mi < 8; ++mi) {
#pragma unroll
            for (int v = 0; v < 4; ++v) {
                C[(size_t)(row0 + mi * 16 + v) * N_DIM + col] = acc[mi][ni][v] + bv;
            }
        }
    }
}

extern "C" void kernel_launch(void* const* d_in, const int* in_sizes, int n_in,
                              void* d_out, int out_size, void* d_ws, size_t ws_size,
                              hipStream_t stream) {
    const float* x    = (const float*)d_in[0];   // [4,2048,4096] f32
    const int*   wq   = (const int*)d_in[1];     // [11008,4096] int32 in 0..15
    const float* am   = (const float*)d_in[2];   // [11008,64] f32
    const float* bias = (const float*)d_in[3];   // [11008] f32
    float* out = (float*)d_out;                  // [4,2048,11008] f32

    const size_t w_elems = (size_t)N_DIM * K_DIM;
    const size_t x_elems = (size_t)M_DIM * K_DIM;
    const size_t need = (w_elems + x_elems) * sizeof(unsigned short);
    if (ws_size < need) return;

    unsigned short* wbf = (unsigned short*)d_ws;
    unsigned short* xbf = wbf + w_elems;

    nf4_dequant_w<<<(int)(w_elems / 8 / 256), 256, 0, stream>>>(wq, am, wbf);
    x_to_bf16<<<(int)(x_elems / 8 / 256), 256, 0, stream>>>(x, xbf);

    const int grid = (M_DIM / BM) * (N_DIM / BN);   // 32 * 43 = 1376
    gemm256<<<grid, 512, 0, stream>>>(xbf, wbf, bias, out);
}

// Round 5
// 945.301 us; speedup vs baseline: 1.0497x; 1.0497x over previous
//
#include <hip/hip_runtime.h>
#include <hip/hip_bf16.h>
#include <stdint.h>

typedef __attribute__((ext_vector_type(8))) short short8;
typedef __attribute__((ext_vector_type(8))) unsigned short ushort8;
typedef __attribute__((ext_vector_type(4))) float f32x4;

#define K_DIM 4096
#define N_DIM 11008
#define M_DIM 8192
#define BM 256
#define BN 256
#define BK 64
#define TILES (K_DIM / BK)   // 64

__constant__ float c_nf4[16] = {
    -1.0f, -0.6961928009986877f, -0.5250730514526367f, -0.39491748809814453f,
    -0.28444138169288635f, -0.18477343022823334f, -0.09105003625154495f, 0.0f,
    0.07958029955625534f, 0.16093020141124725f, 0.24611230194568634f,
    0.33791524171829224f, 0.44070982933044434f, 0.5626170039176941f,
    0.7229568362236023f, 1.0f};

__device__ __forceinline__ unsigned short f2bf(float f) {
    uint32_t u = __float_as_uint(f);
    u += 0x7fffu + ((u >> 16) & 1u);   // round-to-nearest-even (finite inputs)
    return (unsigned short)(u >> 16);
}

__global__ __launch_bounds__(256) void nf4_dequant_w(const int* __restrict__ q,
                                                     const float* __restrict__ absmax,
                                                     unsigned short* __restrict__ w) {
    __shared__ float lut[16];
    if (threadIdx.x < 16) lut[threadIdx.x] = c_nf4[threadIdx.x];
    __syncthreads();
    size_t t = (size_t)blockIdx.x * 256 + threadIdx.x;
    const int4* q4 = (const int4*)q;
    int4 qa = q4[2 * t];
    int4 qb = q4[2 * t + 1];
    float s = absmax[t >> 3];
    ushort8 o;
    o[0] = f2bf(lut[qa.x & 15] * s);
    o[1] = f2bf(lut[qa.y & 15] * s);
    o[2] = f2bf(lut[qa.z & 15] * s);
    o[3] = f2bf(lut[qa.w & 15] * s);
    o[4] = f2bf(lut[qb.x & 15] * s);
    o[5] = f2bf(lut[qb.y & 15] * s);
    o[6] = f2bf(lut[qb.z & 15] * s);
    o[7] = f2bf(lut[qb.w & 15] * s);
    ((ushort8*)w)[t] = o;
}

__global__ __launch_bounds__(256) void x_to_bf16(const float* __restrict__ x,
                                                 unsigned short* __restrict__ xb) {
    size_t t = (size_t)blockIdx.x * 256 + threadIdx.x;
    const float4* x4 = (const float4*)x;
    float4 a = x4[2 * t];
    float4 b = x4[2 * t + 1];
    ushort8 o;
    o[0] = f2bf(a.x); o[1] = f2bf(a.y); o[2] = f2bf(a.z); o[3] = f2bf(a.w);
    o[4] = f2bf(b.x); o[5] = f2bf(b.y); o[6] = f2bf(b.z); o[7] = f2bf(b.w);
    ((ushort8*)xb)[t] = o;
}

// Stage one K-half sub-tile (256 rows x 32 cols bf16 = 16 KB, contiguous LDS):
// 2 global_load_lds x 512 threads x 16B. LDS dest linear (HW: base + lane*16B).
// kcol0 = absolute K start of the 32-col half.
#define STAGE_SUB(gbase, lds_sub, kcol0)                                      \
  do {                                                                        \
    _Pragma("unroll")                                                         \
    for (int _g = 0; _g < 2; ++_g) {                                          \
      const int _i = _g * 512 + tid;       /* 0..1023 */                      \
      const int _r = _i >> 2;              /* row 0..255 */                   \
      const int _c = (_i & 3) << 3;        /* col elem 0,8,16,24 */           \
      __builtin_amdgcn_global_load_lds(                                       \
          (const __attribute__((address_space(1))) void*)((gbase) +           \
              (size_t)_r * K_DIM + (kcol0) + _c),                             \
          (__attribute__((address_space(3))) void*)((lds_sub) +               \
              (_g * 512 + wave * 64) * 8),                                    \
          16, 0, 0);                                                          \
    }                                                                         \
  } while (0)

#define DS_A4(sub, rbase)                                                     \
  af[0] = *(const short8*)((sub) + ((rbase) +  0 + lr) * 32 + q8);            \
  af[1] = *(const short8*)((sub) + ((rbase) + 16 + lr) * 32 + q8);            \
  af[2] = *(const short8*)((sub) + ((rbase) + 32 + lr) * 32 + q8);            \
  af[3] = *(const short8*)((sub) + ((rbase) + 48 + lr) * 32 + q8);

#define DS_B4(sub)                                                            \
  bfr[0] = *(const short8*)((sub) + (wn * 64 +  0 + lr) * 32 + q8);           \
  bfr[1] = *(const short8*)((sub) + (wn * 64 + 16 + lr) * 32 + q8);           \
  bfr[2] = *(const short8*)((sub) + (wn * 64 + 32 + lr) * 32 + q8);           \
  bfr[3] = *(const short8*)((sub) + (wn * 64 + 48 + lr) * 32 + q8);

#define MFMA16(MI0)                                                           \
  do {                                                                        \
    _Pragma("unroll")                                                         \
    for (int _m = 0; _m < 4; ++_m) {                                          \
      _Pragma("unroll")                                                       \
      for (int _n = 0; _n < 4; ++_n)                                          \
        acc[(MI0) + _m][_n] = __builtin_amdgcn_mfma_f32_16x16x32_bf16(        \
            af[_m], bfr[_n], acc[(MI0) + _m][_n], 0, 0, 0);                   \
    }                                                                         \
  } while (0)

#define MIDBAR_MFMA(MI0)                                                      \
  asm volatile("s_barrier" ::: "memory");                                     \
  asm volatile("s_waitcnt lgkmcnt(0)" ::: "memory");                          \
  __builtin_amdgcn_sched_barrier(0);                                          \
  __builtin_amdgcn_s_setprio(1);                                              \
  MFMA16(MI0);                                                                \
  __builtin_amdgcn_s_setprio(0);                                              \
  __builtin_amdgcn_sched_barrier(0);                                          \
  asm volatile("s_barrier" ::: "memory");

// 256x256 tile, BK=64, 8 waves (2M x 4N), dbuf-2 with K-half sub-tile LDS,
// 4 phases/K-tile (16 MFMA each), counted vmcnt(4) twice per tile, never 0.
__global__ __launch_bounds__(512, 2) void gemm256(const unsigned short* __restrict__ A,
                                                  const unsigned short* __restrict__ B,
                                                  const float* __restrict__ bias,
                                                  float* __restrict__ C) {
    // [buf][khalf][256*32] bf16: 4 x 16 KB per operand -> 128 KB total.
    __shared__ unsigned short As[2][2][BM * 32];
    __shared__ unsigned short Bs[2][2][BN * 32];

    const int tid  = threadIdx.x;
    const int wave = tid >> 6;
    const int lane = tid & 63;
    const int wm = wave >> 2;               // 0..1 -> 128-row slab of A
    const int wn = wave & 3;                // 0..3 -> 64-row slab of B
    const int lr = lane & 15;
    const int q8 = (lane >> 4) << 3;        // k elem offset within 32-col half

    // XCD-aware bijective swizzle: grid = 1376, 1376 % 8 == 0.
    const int nbn = N_DIM / BN;             // 43
    const int cpx = (int)gridDim.x >> 3;    // 172
    const int bid = (int)blockIdx.x;
    const int swz = (bid & 7) * cpx + (bid >> 3);
    const int bm = swz / nbn;
    const int bn = swz % nbn;

    const unsigned short* Ab = A + (size_t)bm * BM * K_DIM;
    const unsigned short* Bb = B + (size_t)bn * BN * K_DIM;

    f32x4 acc[8][4];
#pragma unroll
    for (int i = 0; i < 8; ++i)
#pragma unroll
        for (int j = 0; j < 4; ++j)
#pragma unroll
            for (int v = 0; v < 4; ++v) acc[i][j][v] = 0.0f;

    // Prologue: halves t0{A0,B0,A1,B1}, t1{A0,B0} (12 loads/wave).
    STAGE_SUB(Ab, &As[0][0][0], 0);        // t0 h0: A K[0:32)
    STAGE_SUB(Bb, &Bs[0][0][0], 0);        // t0 h1: B K[0:32)
    STAGE_SUB(Ab, &As[0][1][0], 32);       // t0 h2: A K[32:64)
    STAGE_SUB(Bb, &Bs[0][1][0], 32);       // t0 h3: B K[32:64)
    STAGE_SUB(Ab, &As[1][0][0], BK);       // t1 h0
    STAGE_SUB(Bb, &Bs[1][0][0], BK);       // t1 h1
    asm volatile("s_waitcnt vmcnt(4)" ::: "memory");  // t0 fully landed
    asm volatile("s_barrier" ::: "memory");
    // Loop invariant at group t entry: tile t landed+retired; outstanding
    // (per wave) = {t+1 h0, t+1 h1} = 4 loads.

    short8 af[4], bfr[4];

#pragma unroll 1
    for (int t = 0; t < TILES; ++t) {
        const int p = t & 1;
        int t1 = t + 1; if (t1 >= TILES) t1 -= TILES;   // tail wrap: harmless
        int t2 = t + 2; if (t2 >= TILES) t2 -= TILES;   // in-bounds garbage
        const int p1 = t1 & 1;
        const int p2 = t2 & 1;

        // ---- phase 0: mi 0..3, kk=0 (sub 0); stage t+1 h2 (A sub1) ----
        DS_A4(&As[p][0][0], wm * 128);
        DS_B4(&Bs[p][0][0]);
        STAGE_SUB(Ab, &As[p1][1][0], t1 * BK + 32);
        MIDBAR_MFMA(0);

        // ---- phase 1: mi 4..7, kk=0; stage t+1 h3 (B sub1); vmcnt ----
        DS_A4(&As[p][0][0], wm * 128 + 64);
        STAGE_SUB(Bb, &Bs[p1][1][0], t1 * BK + 32);
        // outstanding 8 -> 4: retires t+1{h0,h1} (needed at group t+1 ph0).
        asm volatile("s_waitcnt vmcnt(4)" ::: "memory");
        MIDBAR_MFMA(4);

        // ---- phase 2: mi 0..3, kk=32 (sub 1); stage t+2 h0 (A sub0 of
        //      CURRENT buf p — its readers finished at ph1's end barrier) ----
        DS_A4(&As[p][1][0], wm * 128);
        DS_B4(&Bs[p][1][0]);
        STAGE_SUB(Ab, &As[p2][0][0], t2 * BK);
        MIDBAR_MFMA(0);

        // ---- phase 3: mi 4..7, kk=32; stage t+2 h1 (B sub0); vmcnt ----
        DS_A4(&As[p][1][0], wm * 128 + 64);
        STAGE_SUB(Bb, &Bs[p2][0][0], t2 * BK);
        // outstanding 8 -> 4: retires t+1{h2,h3} (needed at group t+1 ph2).
        asm volatile("s_waitcnt vmcnt(4)" ::: "memory");
        MIDBAR_MFMA(4);
    }
    // Drain remaining DMA before block retire (LDS dealloc safety).
    asm volatile("s_waitcnt vmcnt(0)" ::: "memory");

    // Epilogue: C/D layout col = lane&15, row = (lane>>4)*4 + v (m89/m91).
    const int row0 = bm * BM + wm * 128 + ((lane >> 4) << 2);
    const int col0 = bn * BN + wn * 64 + lr;
#pragma unroll
    for (int ni = 0; ni < 4; ++ni) {
        const int col = col0 + ni * 16;
        const float bv = bias[col];
#pragma unroll
        for (int mi = 0; mi < 8; ++mi) {
#pragma unroll
            for (int v = 0; v < 4; ++v) {
                C[(size_t)(row0 + mi * 16 + v) * N_DIM + col] = acc[mi][ni][v] + bv;
            }
        }
    }
}

extern "C" void kernel_launch(void* const* d_in, const int* in_sizes, int n_in,
                              void* d_out, int out_size, void* d_ws, size_t ws_size,
                              hipStream_t stream) {
    const float* x    = (const float*)d_in[0];   // [4,2048,4096] f32
    const int*   wq   = (const int*)d_in[1];     // [11008,4096] int32 in 0..15
    const float* am   = (const float*)d_in[2];   // [11008,64] f32
    const float* bias = (const float*)d_in[3];   // [11008] f32
    float* out = (float*)d_out;                  // [4,2048,11008] f32

    const size_t w_elems = (size_t)N_DIM * K_DIM;
    const size_t x_elems = (size_t)M_DIM * K_DIM;
    const size_t need = (w_elems + x_elems) * sizeof(unsigned short);
    if (ws_size < need) return;

    unsigned short* wbf = (unsigned short*)d_ws;
    unsigned short* xbf = wbf + w_elems;

    nf4_dequant_w<<<(int)(w_elems / 8 / 256), 256, 0, stream>>>(wq, am, wbf);
    x_to_bf16<<<(int)(x_elems / 8 / 256), 256, 0, stream>>>(x, xbf);

    const int grid = (M_DIM / BM) * (N_DIM / BN);   // 32 * 43 = 1376
    gemm256<<<grid, 512, 0, stream>>>(xbf, wbf, bias, out);
}

// Round 6
// 880.878 us; speedup vs baseline: 1.1265x; 1.0731x over previous
//
#include <hip/hip_runtime.h>
#include <hip/hip_bf16.h>
#include <stdint.h>

typedef __attribute__((ext_vector_type(8))) short short8;
typedef __attribute__((ext_vector_type(8))) unsigned short ushort8;
typedef __attribute__((ext_vector_type(4))) float f32x4;

#define K_DIM 4096
#define N_DIM 11008
#define M_DIM 8192
#define BM 256
#define BN 256
#define BK 64
#define TILES (K_DIM / BK)   // 64

__constant__ float c_nf4[16] = {
    -1.0f, -0.6961928009986877f, -0.5250730514526367f, -0.39491748809814453f,
    -0.28444138169288635f, -0.18477343022823334f, -0.09105003625154495f, 0.0f,
    0.07958029955625534f, 0.16093020141124725f, 0.24611230194568634f,
    0.33791524171829224f, 0.44070982933044434f, 0.5626170039176941f,
    0.7229568362236023f, 1.0f};

__device__ __forceinline__ unsigned short f2bf(float f) {
    uint32_t u = __float_as_uint(f);
    u += 0x7fffu + ((u >> 16) & 1u);   // round-to-nearest-even (finite inputs)
    return (unsigned short)(u >> 16);
}

__global__ __launch_bounds__(256) void nf4_dequant_w(const int* __restrict__ q,
                                                     const float* __restrict__ absmax,
                                                     unsigned short* __restrict__ w) {
    __shared__ float lut[16];
    if (threadIdx.x < 16) lut[threadIdx.x] = c_nf4[threadIdx.x];
    __syncthreads();
    size_t t = (size_t)blockIdx.x * 256 + threadIdx.x;
    const int4* q4 = (const int4*)q;
    int4 qa = q4[2 * t];
    int4 qb = q4[2 * t + 1];
    float s = absmax[t >> 3];
    ushort8 o;
    o[0] = f2bf(lut[qa.x & 15] * s);
    o[1] = f2bf(lut[qa.y & 15] * s);
    o[2] = f2bf(lut[qa.z & 15] * s);
    o[3] = f2bf(lut[qa.w & 15] * s);
    o[4] = f2bf(lut[qb.x & 15] * s);
    o[5] = f2bf(lut[qb.y & 15] * s);
    o[6] = f2bf(lut[qb.z & 15] * s);
    o[7] = f2bf(lut[qb.w & 15] * s);
    ((ushort8*)w)[t] = o;
}

__global__ __launch_bounds__(256) void x_to_bf16(const float* __restrict__ x,
                                                 unsigned short* __restrict__ xb) {
    size_t t = (size_t)blockIdx.x * 256 + threadIdx.x;
    const float4* x4 = (const float4*)x;
    float4 a = x4[2 * t];
    float4 b = x4[2 * t + 1];
    ushort8 o;
    o[0] = f2bf(a.x); o[1] = f2bf(a.y); o[2] = f2bf(a.z); o[3] = f2bf(a.w);
    o[4] = f2bf(b.x); o[5] = f2bf(b.y); o[6] = f2bf(b.z); o[7] = f2bf(b.w);
    ((ushort8*)xb)[t] = o;
}

// Stage one 128-row half [128][64] (16 KB) of a 256-row tile: 2 gloads/thread.
// LDS dest linear (HW: wave-uniform base + lane*16B); GLOBAL source chunk
// G4-swizzled (r4-proven zero-conflict): LDS slot (r, s) holds chunk s^(r&7).
#define STAGE_HALF(gbase, lds_half, row0, k0)                                 \
  do {                                                                        \
    _Pragma("unroll")                                                         \
    for (int _g = 0; _g < 2; ++_g) {                                          \
      const int _i = _g * 512 + tid;       /* slot 0..1023 */                 \
      const int _r = _i >> 3;              /* local row 0..127 */             \
      const int _c = (_i & 7) ^ (_r & 7);  /* global chunk */                 \
      __builtin_amdgcn_global_load_lds(                                       \
          (const __attribute__((address_space(1))) void*)((gbase) +           \
              (size_t)((row0) + _r) * K_DIM + (k0) + _c * 8),                 \
          (__attribute__((address_space(3))) void*)((lds_half) +              \
              (_g * 512 + wave * 64) * 8),                                    \
          16, 0, 0);                                                          \
    }                                                                         \
  } while (0)

// Frag reads from a [128][64] half; row = rbase + lr; swizzled chunk slot.
#define DS_A4(rbase, X)                                                       \
  af[0] = *(const short8*)(Ah + ((rbase) +  0) * 64 + (roff ^ (X)));          \
  af[1] = *(const short8*)(Ah + ((rbase) + 16) * 64 + (roff ^ (X)));          \
  af[2] = *(const short8*)(Ah + ((rbase) + 32) * 64 + (roff ^ (X)));          \
  af[3] = *(const short8*)(Ah + ((rbase) + 48) * 64 + (roff ^ (X)));

#define DS_B4(X)                                                              \
  bfr[0] = *(const short8*)(Bh + (bbase +  0) * 64 + (roff ^ (X)));           \
  bfr[1] = *(const short8*)(Bh + (bbase + 16) * 64 + (roff ^ (X)));           \
  bfr[2] = *(const short8*)(Bh + (bbase + 32) * 64 + (roff ^ (X)));           \
  bfr[3] = *(const short8*)(Bh + (bbase + 48) * 64 + (roff ^ (X)));

#define MFMA16(MI0)                                                           \
  __builtin_amdgcn_s_setprio(1);                                              \
  do {                                                                        \
    _Pragma("unroll")                                                         \
    for (int _m = 0; _m < 4; ++_m) {                                          \
      _Pragma("unroll")                                                       \
      for (int _n = 0; _n < 4; ++_n)                                          \
        acc[(MI0) + _m][_n] = __builtin_amdgcn_mfma_f32_16x16x32_bf16(        \
            af[_m], bfr[_n], acc[(MI0) + _m][_n], 0, 0, 0);                   \
    }                                                                         \
  } while (0);                                                                \
  __builtin_amdgcn_s_setprio(0);

// 256x256 tile, BK=64, 8 waves (2M x 4N), dbuf-2 row-half LDS, G4 swizzle,
// LOOSE GROUP: zero intra-tile barriers; 1 barrier + lgkm(0) + vmcnt(0) per
// K-tile (drain waits on loads issued 2-3 phases earlier -> free).
__global__ __launch_bounds__(512, 2) void gemm256(const unsigned short* __restrict__ A,
                                                  const unsigned short* __restrict__ B,
                                                  const float* __restrict__ bias,
                                                  float* __restrict__ C) {
    // [buf][row-half][128*64] bf16: 4 x 16 KB per operand -> 128 KB total.
    __shared__ unsigned short As[2][2][128 * 64];
    __shared__ unsigned short Bs[2][2][128 * 64];

    const int tid  = threadIdx.x;
    const int wave = tid >> 6;
    const int lane = tid & 63;
    const int wm = wave >> 2;               // 0..1 -> A row-half
    const int wn = wave & 3;                // 0..3 -> 64-row B slab
    const int lr = lane & 15;
    const int q  = lane >> 4;               // 0..3
    // Zero-conflict swizzled read offset (elements), kk=0; kk=32 -> roff^32.
    const int roff = lr * 64 + ((q ^ (lr & 7)) << 3);
    const int bbase = (wn & 1) * 64;        // B row base within its half

    // XCD-aware bijective swizzle: grid = 1376, 1376 % 8 == 0.
    const int nbn = N_DIM / BN;             // 43
    const int cpx = (int)gridDim.x >> 3;    // 172
    const int bid = (int)blockIdx.x;
    const int swz = (bid & 7) * cpx + (bid >> 3);
    const int bm = swz / nbn;
    const int bn = swz % nbn;

    const unsigned short* Ab = A + (size_t)bm * BM * K_DIM;
    const unsigned short* Bb = B + (size_t)bn * BN * K_DIM;

    f32x4 acc[8][4];
#pragma unroll
    for (int i = 0; i < 8; ++i)
#pragma unroll
        for (int j = 0; j < 4; ++j)
#pragma unroll
            for (int v = 0; v < 4; ++v) acc[i][j][v] = 0.0f;

    // Prologue: stage tile 0 (4 halves, 8 loads/thread); drain; barrier.
    STAGE_HALF(Ab, &As[0][0][0], 0,   0); STAGE_HALF(Bb, &Bs[0][0][0], 0,   0);
    STAGE_HALF(Ab, &As[0][1][0], 128, 0); STAGE_HALF(Bb, &Bs[0][1][0], 128, 0);
    asm volatile("s_waitcnt vmcnt(0)" ::: "memory");
    asm volatile("s_barrier" ::: "memory");

    short8 af[4], bfr[4];

#pragma unroll 1
    for (int t = 0; t < TILES; ++t) {
        const int p = t & 1;
        int t1 = t + 1; if (t1 >= TILES) t1 = 0;   // tail wrap: harmless
        const int k1 = t1 * BK;
        const unsigned short* Ah = &As[p][wm][0];
        const unsigned short* Bh = &Bs[p][wn >> 1][0];

        // ---- phase 0: mi 0..3, kk=0; stage t+1 A-h0 + B-h0 ----
        DS_A4(0, 0);
        DS_B4(0);
        STAGE_HALF(Ab, &As[p ^ 1][0][0], 0, k1);
        STAGE_HALF(Bb, &Bs[p ^ 1][0][0], 0, k1);
        MFMA16(0);

        // ---- phase 1: mi 4..7, kk=0; stage t+1 A-h1 + B-h1 ----
        DS_A4(64, 0);
        STAGE_HALF(Ab, &As[p ^ 1][1][0], 128, k1);
        STAGE_HALF(Bb, &Bs[p ^ 1][1][0], 128, k1);
        MFMA16(4);

        // ---- phase 2: mi 0..3, kk=32 ----
        DS_A4(0, 32);
        DS_B4(32);
        MFMA16(0);

        // ---- phase 3: mi 4..7, kk=32 ----
        DS_A4(64, 32);
        MFMA16(4);

        // Group boundary: (rule 18) pin read-completion before barrier
        // arrival; vmcnt(0) waits on loads issued ~2-3 phases ago -> ~free.
        asm volatile("s_waitcnt lgkmcnt(0)" ::: "memory");
        __builtin_amdgcn_sched_barrier(0);
        asm volatile("s_waitcnt vmcnt(0)" ::: "memory");
        asm volatile("s_barrier" ::: "memory");
    }

    // Epilogue: C/D layout col = lane&15, row = (lane>>4)*4 + v (m89/m91).
    const int row0 = bm * BM + wm * 128 + (q << 2);
    const int col0 = bn * BN + wn * 64 + lr;
#pragma unroll
    for (int ni = 0; ni < 4; ++ni) {
        const int col = col0 + ni * 16;
        const float bv = bias[col];
#pragma unroll
        for (int mi = 0; mi < 8; ++mi) {
#pragma unroll
            for (int v = 0; v < 4; ++v) {
                C[(size_t)(row0 + mi * 16 + v) * N_DIM + col] = acc[mi][ni][v] + bv;
            }
        }
    }
}

extern "C" void kernel_launch(void* const* d_in, const int* in_sizes, int n_in,
                              void* d_out, int out_size, void* d_ws, size_t ws_size,
                              hipStream_t stream) {
    const float* x    = (const float*)d_in[0];   // [4,2048,4096] f32
    const int*   wq   = (const int*)d_in[1];     // [11008,4096] int32 in 0..15
    const float* am   = (const float*)d_in[2];   // [11008,64] f32
    const float* bias = (const float*)d_in[3];   // [11008] f32
    float* out = (float*)d_out;                  // [4,2048,11008] f32

    const size_t w_elems = (size_t)N_DIM * K_DIM;
    const size_t x_elems = (size_t)M_DIM * K_DIM;
    const size_t need = (w_elems + x_elems) * sizeof(unsigned short);
    if (ws_size < need) return;

    unsigned short* wbf = (unsigned short*)d_ws;
    unsigned short* xbf = wbf + w_elems;

    nf4_dequant_w<<<(int)(w_elems / 8 / 256), 256, 0, stream>>>(wq, am, wbf);
    x_to_bf16<<<(int)(x_elems / 8 / 256), 256, 0, stream>>>(x, xbf);

    const int grid = (M_DIM / BM) * (N_DIM / BN);   // 32 * 43 = 1376
    gemm256<<<grid, 512, 0, stream>>>(xbf, wbf, bias, out);
}

// Round 7
// 815.693 us; speedup vs baseline: 1.2165x; 1.0799x over previous
//
#include <hip/hip_runtime.h>
#include <hip/hip_bf16.h>
#include <stdint.h>

typedef __attribute__((ext_vector_type(8))) short short8;
typedef __attribute__((ext_vector_type(8))) unsigned short ushort8;
typedef __attribute__((ext_vector_type(4))) float f32x4;

#define K_DIM 4096
#define N_DIM 11008
#define M_DIM 8192
#define BM 256
#define BN 256
#define BK 64
#define TILES (K_DIM / BK)   // 64

__constant__ float c_nf4[16] = {
    -1.0f, -0.6961928009986877f, -0.5250730514526367f, -0.39491748809814453f,
    -0.28444138169288635f, -0.18477343022823334f, -0.09105003625154495f, 0.0f,
    0.07958029955625534f, 0.16093020141124725f, 0.24611230194568634f,
    0.33791524171829224f, 0.44070982933044434f, 0.5626170039176941f,
    0.7229568362236023f, 1.0f};

__device__ __forceinline__ unsigned short f2bf(float f) {
    uint32_t u = __float_as_uint(f);
    u += 0x7fffu + ((u >> 16) & 1u);   // round-to-nearest-even (finite inputs)
    return (unsigned short)(u >> 16);
}

__global__ __launch_bounds__(256) void nf4_dequant_w(const int* __restrict__ q,
                                                     const float* __restrict__ absmax,
                                                     unsigned short* __restrict__ w) {
    __shared__ float lut[16];
    if (threadIdx.x < 16) lut[threadIdx.x] = c_nf4[threadIdx.x];
    __syncthreads();
    size_t t = (size_t)blockIdx.x * 256 + threadIdx.x;
    const int4* q4 = (const int4*)q;
    int4 qa = q4[2 * t];
    int4 qb = q4[2 * t + 1];
    float s = absmax[t >> 3];
    ushort8 o;
    o[0] = f2bf(lut[qa.x & 15] * s);
    o[1] = f2bf(lut[qa.y & 15] * s);
    o[2] = f2bf(lut[qa.z & 15] * s);
    o[3] = f2bf(lut[qa.w & 15] * s);
    o[4] = f2bf(lut[qb.x & 15] * s);
    o[5] = f2bf(lut[qb.y & 15] * s);
    o[6] = f2bf(lut[qb.z & 15] * s);
    o[7] = f2bf(lut[qb.w & 15] * s);
    ((ushort8*)w)[t] = o;
}

__global__ __launch_bounds__(256) void x_to_bf16(const float* __restrict__ x,
                                                 unsigned short* __restrict__ xb) {
    size_t t = (size_t)blockIdx.x * 256 + threadIdx.x;
    const float4* x4 = (const float4*)x;
    float4 a = x4[2 * t];
    float4 b = x4[2 * t + 1];
    ushort8 o;
    o[0] = f2bf(a.x); o[1] = f2bf(a.y); o[2] = f2bf(a.z); o[3] = f2bf(a.w);
    o[4] = f2bf(b.x); o[5] = f2bf(b.y); o[6] = f2bf(b.z); o[7] = f2bf(b.w);
    ((ushort8*)xb)[t] = o;
}

// Stage one 128-row half [128][64] (16 KB): 2 gloads/thread, LDS dest linear,
// GLOBAL source chunk G4-swizzled (r4/r6-proven zero-conflict):
// LDS slot (r, s) holds global chunk s ^ (r&7).
#define STAGE_HALF(gbase, lds_half, row0, k0)                                 \
  do {                                                                        \
    _Pragma("unroll")                                                         \
    for (int _g = 0; _g < 2; ++_g) {                                          \
      const int _i = _g * 512 + tid;       /* slot 0..1023 */                 \
      const int _r = _i >> 3;              /* local row 0..127 */             \
      const int _c = (_i & 7) ^ (_r & 7);  /* global chunk */                 \
      __builtin_amdgcn_global_load_lds(                                       \
          (const __attribute__((address_space(1))) void*)((gbase) +           \
              (size_t)((row0) + _r) * K_DIM + (k0) + _c * 8),                 \
          (__attribute__((address_space(3))) void*)((lds_half) +              \
              (_g * 512 + wave * 64) * 8),                                    \
          16, 0, 0);                                                          \
    }                                                                         \
  } while (0)

// Frag reads from a [128][64] half into a NAMED register set (rule 20).
#define DS_A4(dst, rbase, X)                                                  \
  dst[0] = *(const short8*)(Ah + ((rbase) +  0) * 64 + (roff ^ (X)));         \
  dst[1] = *(const short8*)(Ah + ((rbase) + 16) * 64 + (roff ^ (X)));         \
  dst[2] = *(const short8*)(Ah + ((rbase) + 32) * 64 + (roff ^ (X)));         \
  dst[3] = *(const short8*)(Ah + ((rbase) + 48) * 64 + (roff ^ (X)));

#define DS_B4(dst, X)                                                         \
  dst[0] = *(const short8*)(Bh + (bbase +  0) * 64 + (roff ^ (X)));           \
  dst[1] = *(const short8*)(Bh + (bbase + 16) * 64 + (roff ^ (X)));           \
  dst[2] = *(const short8*)(Bh + (bbase + 32) * 64 + (roff ^ (X)));           \
  dst[3] = *(const short8*)(Bh + (bbase + 48) * 64 + (roff ^ (X)));

#define MFMA16(MI0, Ar, Br)                                                   \
  __builtin_amdgcn_s_setprio(1);                                              \
  do {                                                                        \
    _Pragma("unroll")                                                         \
    for (int _m = 0; _m < 4; ++_m) {                                          \
      _Pragma("unroll")                                                       \
      for (int _n = 0; _n < 4; ++_n)                                          \
        acc[(MI0) + _m][_n] = __builtin_amdgcn_mfma_f32_16x16x32_bf16(        \
            Ar[_m], Br[_n], acc[(MI0) + _m][_n], 0, 0, 0);                    \
    }                                                                         \
  } while (0);                                                                \
  __builtin_amdgcn_s_setprio(0);

// 256x256 tile, BK=64, 8 waves (2M x 4N), dbuf-2, G4 swizzle, loose group
// (1 barrier/tile), REGISTER-PIPELINED operands: dedicated sets per phase so
// ds_reads of phase i+1.. stream inside the MFMA shadow (no WAR lockstep).
__global__ __launch_bounds__(512, 2) void gemm256(const unsigned short* __restrict__ A,
                                                  const unsigned short* __restrict__ B,
                                                  const float* __restrict__ bias,
                                                  float* __restrict__ C) {
    __shared__ unsigned short As[2][2][128 * 64];   // [buf][row-half], 64 KB
    __shared__ unsigned short Bs[2][2][128 * 64];   // 64 KB -> 128 KB total

    const int tid  = threadIdx.x;
    const int wave = tid >> 6;
    const int lane = tid & 63;
    const int wm = wave >> 2;               // 0..1 -> A row-half
    const int wn = wave & 3;                // 0..3 -> 64-row B slab
    const int lr = lane & 15;
    const int q  = lane >> 4;               // 0..3
    // Zero-conflict swizzled read offset (elements), kk=0; kk=32 -> roff^32.
    const int roff = lr * 64 + ((q ^ (lr & 7)) << 3);
    const int bbase = (wn & 1) * 64;        // B row base within its half

    // XCD-aware bijective swizzle: grid = 1376, 1376 % 8 == 0.
    const int nbn = N_DIM / BN;             // 43
    const int cpx = (int)gridDim.x >> 3;    // 172
    const int bid = (int)blockIdx.x;
    const int swz = (bid & 7) * cpx + (bid >> 3);
    const int bm = swz / nbn;
    const int bn = swz % nbn;

    const unsigned short* Ab = A + (size_t)bm * BM * K_DIM;
    const unsigned short* Bb = B + (size_t)bn * BN * K_DIM;

    f32x4 acc[8][4];
#pragma unroll
    for (int i = 0; i < 8; ++i)
#pragma unroll
        for (int j = 0; j < 4; ++j)
#pragma unroll
            for (int v = 0; v < 4; ++v) acc[i][j][v] = 0.0f;

    // Prologue: stage tile 0 (4 halves, 8 loads/thread); drain; barrier.
    STAGE_HALF(Ab, &As[0][0][0], 0,   0); STAGE_HALF(Bb, &Bs[0][0][0], 0,   0);
    STAGE_HALF(Ab, &As[0][1][0], 128, 0); STAGE_HALF(Bb, &Bs[0][1][0], 128, 0);
    asm volatile("s_waitcnt vmcnt(0)" ::: "memory");
    asm volatile("s_barrier" ::: "memory");

    // Dedicated operand register sets (liveness-disjoint across clusters).
    short8 aA[4], aB[4], aC[4], aD[4], bE[4], bO[4];

#pragma unroll 1
    for (int t = 0; t < TILES; ++t) {
        const int p = t & 1;
        int t1 = t + 1; if (t1 >= TILES) t1 = 0;   // tail wrap: harmless
        const int k1 = t1 * BK;
        const unsigned short* Ah = &As[p][wm][0];
        const unsigned short* Bh = &Bs[p][wn >> 1][0];

        // Front-loaded reads for clusters 0 and 1 (12 x ds_read_b128).
        DS_A4(aA, 0, 0);        // A rows 0..63,  kk=0
        DS_B4(bE, 0);           // B kk=0 (shared by clusters 0,1)
        DS_A4(aB, 64, 0);       // A rows 64..127, kk=0

        // Stage tile t+1 into the other buffer (8 gloads, land by tile end).
        STAGE_HALF(Ab, &As[p ^ 1][0][0], 0,   k1);
        STAGE_HALF(Bb, &Bs[p ^ 1][0][0], 0,   k1);
        STAGE_HALF(Ab, &As[p ^ 1][1][0], 128, k1);
        STAGE_HALF(Bb, &Bs[p ^ 1][1][0], 128, k1);

        MFMA16(0, aA, bE);      // cluster 0

        // These stream in cluster-0/1's shadow (dedicated regs, no WAR).
        DS_B4(bO, 32);          // B kk=32
        DS_A4(aC, 0, 32);       // A rows 0..63,  kk=32

        MFMA16(4, aB, bE);      // cluster 1

        DS_A4(aD, 64, 32);      // A rows 64..127, kk=32

        MFMA16(0, aC, bO);      // cluster 2
        MFMA16(4, aD, bO);      // cluster 3

        // Group boundary: pin read completion (rule 18), then free drain
        // (vmcnt(0) waits on loads issued a full tile ago) + barrier.
        asm volatile("s_waitcnt lgkmcnt(0)" ::: "memory");
        __builtin_amdgcn_sched_barrier(0);
        asm volatile("s_waitcnt vmcnt(0)" ::: "memory");
        asm volatile("s_barrier" ::: "memory");
    }

    // Epilogue: C/D layout col = lane&15, row = (lane>>4)*4 + v (m89/m91).
    const int row0 = bm * BM + wm * 128 + (q << 2);
    const int col0 = bn * BN + wn * 64 + lr;
#pragma unroll
    for (int ni = 0; ni < 4; ++ni) {
        const int col = col0 + ni * 16;
        const float bv = bias[col];
#pragma unroll
        for (int mi = 0; mi < 8; ++mi) {
#pragma unroll
            for (int v = 0; v < 4; ++v) {
                C[(size_t)(row0 + mi * 16 + v) * N_DIM + col] = acc[mi][ni][v] + bv;
            }
        }
    }
}

extern "C" void kernel_launch(void* const* d_in, const int* in_sizes, int n_in,
                              void* d_out, int out_size, void* d_ws, size_t ws_size,
                              hipStream_t stream) {
    const float* x    = (const float*)d_in[0];   // [4,2048,4096] f32
    const int*   wq   = (const int*)d_in[1];     // [11008,4096] int32 in 0..15
    const float* am   = (const float*)d_in[2];   // [11008,64] f32
    const float* bias = (const float*)d_in[3];   // [11008] f32
    float* out = (float*)d_out;                  // [4,2048,11008] f32

    const size_t w_elems = (size_t)N_DIM * K_DIM;
    const size_t x_elems = (size_t)M_DIM * K_DIM;
    const size_t need = (w_elems + x_elems) * sizeof(unsigned short);
    if (ws_size < need) return;

    unsigned short* wbf = (unsigned short*)d_ws;
    unsigned short* xbf = wbf + w_elems;

    nf4_dequant_w<<<(int)(w_elems / 8 / 256), 256, 0, stream>>>(wq, am, wbf);
    x_to_bf16<<<(int)(x_elems / 8 / 256), 256, 0, stream>>>(x, xbf);

    const int grid = (M_DIM / BM) * (N_DIM / BN);   // 32 * 43 = 1376
    gemm256<<<grid, 512, 0, stream>>>(xbf, wbf, bias, out);
}